// Round 9
// baseline (114.840 us; speedup 1.0000x reference)
//
#include <hip/hip_runtime.h>
#include <hip/hip_bf16.h>
#include <math.h>

#define BB 4
#define CC 64
#define DD 8
#define NN 4096
#define KS 8
#define KPS (NN / KS)          // 512 keys per split
#define LOG2E 1.44269504088896340736f

typedef __attribute__((ext_vector_type(4))) short short4v;      // 4 bf16
typedef __attribute__((ext_vector_type(8))) unsigned short ushort8;  // 16B
typedef __attribute__((ext_vector_type(16))) float f32x16;

// Device-pass-only builtins; host pass still semantic-checks __global__ bodies.
#if defined(__HIP_DEVICE_COMPILE__)
  #if __has_builtin(__builtin_amdgcn_mfma_f32_32x32x8bf16_1k)
    #define MFMA32x8(A, B, C) __builtin_amdgcn_mfma_f32_32x32x8bf16_1k(A, B, C, 0, 0, 0)
  #elif __has_builtin(__builtin_amdgcn_mfma_f32_32x32x8_bf16)
    #define MFMA32x8(A, B, C) __builtin_amdgcn_mfma_f32_32x32x8_bf16(A, B, C, 0, 0, 0)
  #else
    #error "no 32x32x8 bf16 MFMA builtin in device pass"
  #endif
  #if __has_builtin(__builtin_amdgcn_exp2f)
    #define EXP2(x) __builtin_amdgcn_exp2f(x)   // raw v_exp_f32, no OCML branches
  #else
    #define EXP2(x) exp2f(x)
  #endif
#else
  static __device__ __host__ inline f32x16 MFMA32x8(short4v, short4v, f32x16 c) { return c; }
  #define EXP2(x) exp2f(x)
#endif

static __device__ inline short4v pack4(float a, float b, float c, float d) {
    union { short4v s; __hip_bfloat162 h[2]; } u;
    u.h[0] = __float22bfloat162_rn(make_float2(a, b));
    u.h[1] = __float22bfloat162_rn(make_float2(c, d));
    return u.s;
}

// ---------------------------------------------------------------------------
// Kernel 1: qkv as MFMA GEMM (unchanged from R8).  Y[96pad,N] = [Wv;Wq;Wk]@x.
// W via float4 VECTOR loads (VGPR A-frags, no s_load stalls); x streams as B.
// rt 0/1 -> vT[B][C][N]; rt 2 -> q/k transposed via LDS to [B][N][8].
// Grid: ((ng*3 + rt)*4 + b), ng in [0,32) -> 384 blocks.
// ---------------------------------------------------------------------------
__global__ __launch_bounds__(256) void qkv_kernel(
    const float* __restrict__ x,  const float* __restrict__ Wq, const float* __restrict__ bq,
    const float* __restrict__ Wk, const float* __restrict__ bk,
    const float* __restrict__ Wv, const float* __restrict__ bv,
    unsigned short* __restrict__ qb, unsigned short* __restrict__ kb,
    unsigned short* __restrict__ vT)
{
    __shared__ unsigned short LQ[128 * 8];
    __shared__ unsigned short LK[128 * 8];

    int tid = threadIdx.x;
    int wave = tid >> 6, lane = tid & 63;
    int l32 = lane & 31, h2 = lane >> 5;

    int blk = blockIdx.x;
    int b = blk & (BB - 1);
    int r2 = blk >> 2;
    int rt = r2 % 3;
    int ng = r2 / 3;
    int n0 = ng * 128 + wave * 32;

    short4v af[8];
    #pragma unroll
    for (int s = 0; s < 8; ++s) {
        float4 w4;
        if (rt < 2) {
            w4 = *(const float4*)(Wv + (size_t)(rt * 32 + l32) * CC + s * 8 + 4 * h2);
        } else if (l32 < 8) {
            w4 = *(const float4*)(Wq + (size_t)l32 * CC + s * 8 + 4 * h2);
        } else if (l32 < 16) {
            w4 = *(const float4*)(Wk + (size_t)(l32 - 8) * CC + s * 8 + 4 * h2);
        } else {
            w4 = make_float4(0.f, 0.f, 0.f, 0.f);
        }
        af[s] = pack4(w4.x, w4.y, w4.z, w4.w);
    }

    const float* xb = x + (size_t)b * CC * NN + n0 + l32;
    short4v bf[8];
    #pragma unroll
    for (int s = 0; s < 8; ++s) {
        int c0 = s * 8 + 4 * h2;
        float x0 = xb[(size_t)(c0 + 0) * NN];
        float x1 = xb[(size_t)(c0 + 1) * NN];
        float x2 = xb[(size_t)(c0 + 2) * NN];
        float x3 = xb[(size_t)(c0 + 3) * NN];
        bf[s] = pack4(x0, x1, x2, x3);
    }

    f32x16 acc;
    #pragma unroll
    for (int r = 0; r < 16; ++r) acc[r] = 0.f;
    #pragma unroll
    for (int s = 0; s < 8; ++s)
        acc = MFMA32x8(af[s], bf[s], acc);

    if (rt < 2) {
        #pragma unroll
        for (int r = 0; r < 16; ++r) {
            int row = rt * 32 + (r & 3) + 8 * (r >> 2) + 4 * h2;
            float val = acc[r] + bv[row];
            __hip_bfloat16 hv = __float2bfloat16(val);
            vT[((size_t)b * CC + row) * NN + n0 + l32] = *(unsigned short*)&hv;
        }
    } else {
        short4v qp = pack4((acc[0] + bq[0 + 4 * h2]) * LOG2E,
                           (acc[1] + bq[1 + 4 * h2]) * LOG2E,
                           (acc[2] + bq[2 + 4 * h2]) * LOG2E,
                           (acc[3] + bq[3 + 4 * h2]) * LOG2E);
        short4v kp = pack4(acc[4] + bk[0 + 4 * h2],
                           acc[5] + bk[1 + 4 * h2],
                           acc[6] + bk[2 + 4 * h2],
                           acc[7] + bk[3 + 4 * h2]);
        int nl = wave * 32 + l32;
        *(short4v*)(LQ + (size_t)nl * 8 + 4 * h2) = qp;
        *(short4v*)(LK + (size_t)nl * 8 + 4 * h2) = kp;
        __syncthreads();
        if (tid < 128) {
            ushort8 row = *(const ushort8*)(LQ + (size_t)tid * 8);
            *(ushort8*)(qb + ((size_t)b * NN + ng * 128 + tid) * 8) = row;
        } else {
            int t = tid - 128;
            ushort8 row = *(const ushort8*)(LK + (size_t)t * 8);
            *(ushort8*)(kb + ((size_t)b * NN + ng * 128 + t) * 8) = row;
        }
    }
}

// ---------------------------------------------------------------------------
// Kernel 2: MFMA flash partials. Splits are additive (no max-subtraction),
// so partial O and row-sums go straight into obuf/ssb via native fp32
// atomics (unsafeAtomicAdd -> global_atomic_add_f32) -- no accbuf, no merge
// re-read. V tiles staged in LDS (XOR-swizzled), next tile reg-prefetched.
// exp2 = raw v_exp_f32; 4-way split ssum chain.
// Grid: BB * (N/128) * KS = 1024 blocks.
// ---------------------------------------------------------------------------
__global__ __launch_bounds__(256, 4) void flash_kernel(
    const unsigned short* __restrict__ qb, const unsigned short* __restrict__ kb,
    const unsigned short* __restrict__ vT, float* __restrict__ obuf,
    float* __restrict__ ssb)
{
    __shared__ unsigned short VS[64 * 132];
    int tid = threadIdx.x;
    int wave = tid >> 6, lane = tid & 63;
    int l32 = lane & 31, h2 = lane >> 5;

    int blk = blockIdx.x;            // batch in low 2 bits -> XCD locality
    int b = blk & (BB - 1);
    int rest = blk >> 2;
    int split = rest & (KS - 1);
    int qchunk = rest >> 3;
    int n0 = qchunk * 128 + wave * 32;

    short4v qf = *(const short4v*)(qb + ((size_t)b * NN + n0 + l32) * DD + h2 * 4);

    const unsigned short* kbb = kb + (size_t)b * NN * DD;
    const unsigned short* vbb = vT + (size_t)b * CC * NN;
    int m0 = split * KPS;

    int cch = tid >> 4, kg = tid & 15;
    int kgx = (kg ^ (cch & 3)) * 8;

    f32x16 o0, o1, zz;
    #pragma unroll
    for (int r = 0; r < 16; ++r) { o0[r] = 0.f; o1[r] = 0.f; zz[r] = 0.f; }
    float s0 = 0.f, s1 = 0.f, s2 = 0.f, s3 = 0.f;

    ushort8 vr0 = *(const ushort8*)(vbb + (size_t)(cch)      * NN + m0 + kg * 8);
    ushort8 vr1 = *(const ushort8*)(vbb + (size_t)(16 + cch) * NN + m0 + kg * 8);
    ushort8 vr2 = *(const ushort8*)(vbb + (size_t)(32 + cch) * NN + m0 + kg * 8);
    ushort8 vr3 = *(const ushort8*)(vbb + (size_t)(48 + cch) * NN + m0 + kg * 8);

    for (int tile = 0; tile < 4; ++tile) {
        *(ushort8*)(VS + (size_t)(cch)      * 132 + kgx) = vr0;
        *(ushort8*)(VS + (size_t)(16 + cch) * 132 + kgx) = vr1;
        *(ushort8*)(VS + (size_t)(32 + cch) * 132 + kgx) = vr2;
        *(ushort8*)(VS + (size_t)(48 + cch) * 132 + kgx) = vr3;
        __syncthreads();

        if (tile < 3) {
            int mn = m0 + (tile + 1) * 128;
            vr0 = *(const ushort8*)(vbb + (size_t)(cch)      * NN + mn + kg * 8);
            vr1 = *(const ushort8*)(vbb + (size_t)(16 + cch) * NN + mn + kg * 8);
            vr2 = *(const ushort8*)(vbb + (size_t)(32 + cch) * NN + mn + kg * 8);
            vr3 = *(const ushort8*)(vbb + (size_t)(48 + cch) * NN + mn + kg * 8);
        }

        short4v kf[4];
        #pragma unroll
        for (int s = 0; s < 4; ++s)
            kf[s] = *(const short4v*)(kbb + (size_t)(m0 + tile * 128 + s * 32 + l32) * DD + h2 * 4);

        #pragma unroll
        for (int sub = 0; sub < 4; ++sub) {
            f32x16 st = MFMA32x8(kf[sub], qf, zz);
            float w[16];
            #pragma unroll
            for (int r = 0; r < 16; ++r) w[r] = EXP2(st[r]);
            s0 += (w[0] + w[1]) + (w[2] + w[3]);
            s1 += (w[4] + w[5]) + (w[6] + w[7]);
            s2 += (w[8] + w[9]) + (w[10] + w[11]);
            s3 += (w[12] + w[13]) + (w[14] + w[15]);

            union { short4v s; __hip_bfloat162 h[2]; } u[4];
            #pragma unroll
            for (int g = 0; g < 4; ++g) {
                u[g].h[0] = __float22bfloat162_rn(make_float2(w[4 * g],     w[4 * g + 1]));
                u[g].h[1] = __float22bfloat162_rn(make_float2(w[4 * g + 2], w[4 * g + 3]));
            }
            #pragma unroll
            for (int g = 0; g < 4; ++g) {
                int go = ((sub * 4 + g) ^ (l32 & 3)) * 8 + h2 * 4;
                short4v vf0 = *(const short4v*)(VS + (size_t)(l32)      * 132 + go);
                short4v vf1 = *(const short4v*)(VS + (size_t)(32 + l32) * 132 + go);
                o0 = MFMA32x8(u[g].s, vf0, o0);
                o1 = MFMA32x8(u[g].s, vf1, o1);
            }
        }
        __syncthreads();
    }

    // additive split merge: fp32 atomics into obuf[b][n][c] (8-way temporal
    // contention per address across splits -- trivial for L2 atomics)
    float* ob = obuf + ((size_t)(b * NN + n0)) * CC;
    #pragma unroll
    for (int r = 0; r < 16; ++r) {
        int qrow = (r & 3) + 8 * (r >> 2) + 4 * h2;
        unsafeAtomicAdd(ob + (size_t)qrow * CC + l32,      o0[r]);
        unsafeAtomicAdd(ob + (size_t)qrow * CC + 32 + l32, o1[r]);
    }
    float ssum = (s0 + s1) + (s2 + s3);
    ssum += __shfl_xor(ssum, 32);
    if (lane < 32)
        unsafeAtomicAdd(ssb + (size_t)b * NN + n0 + l32, ssum);
}

// ---------------------------------------------------------------------------
// Kernel 3: normalize + residual.  out[b][c][n] = g*obuf[b][n][c]/ssb[b][n]
// + x[b][c][n].  float4 obuf reads (fully coalesced 1KB/instr), LDS
// transpose, 2x128B out writes/instr.  Grid: B*128 blocks (32 n each).
// ---------------------------------------------------------------------------
__global__ __launch_bounds__(256) void norm_kernel(
    const float* __restrict__ obuf, const float* __restrict__ ssb,
    const float* __restrict__ x, const float* __restrict__ gamma,
    float* __restrict__ out)
{
    __shared__ float tile[32 * 65];
    __shared__ float stl[32];
    int blk = blockIdx.x;            // B * 128
    int b = blk >> 7;
    int n0 = (blk & 127) * 32;
    int tid = threadIdx.x;

    if (tid < 32) stl[tid] = 1.0f / ssb[(size_t)b * NN + n0 + tid];

    int nl = tid >> 4, cg = tid & 15;       // 16 positions/pass, 2 passes
    #pragma unroll
    for (int p = 0; p < 2; ++p) {
        int n = p * 16 + nl;
        float4 v = *(const float4*)(obuf + ((size_t)(b * NN + n0 + n)) * CC + cg * 4);
        tile[n * 65 + cg * 4 + 0] = v.x;
        tile[n * 65 + cg * 4 + 1] = v.y;
        tile[n * 65 + cg * 4 + 2] = v.z;
        tile[n * 65 + cg * 4 + 3] = v.w;
    }
    __syncthreads();
    float g = gamma[0];
    #pragma unroll
    for (int p = 0; p < 8; ++p) {
        int idx = p * 256 + tid;
        int c = idx >> 5, n_l = idx & 31;
        size_t xi = ((size_t)b * CC + c) * NN + n0 + n_l;
        out[xi] = g * tile[n_l * 65 + c] * stl[n_l] + x[xi];
    }
}

// ---------------------------------------------------------------------------
extern "C" void kernel_launch(void* const* d_in, const int* in_sizes, int n_in,
                              void* d_out, int out_size, void* d_ws, size_t ws_size,
                              hipStream_t stream)
{
    const float* x     = (const float*)d_in[0];
    const float* Wq    = (const float*)d_in[1];
    const float* bq    = (const float*)d_in[2];
    const float* Wk    = (const float*)d_in[3];
    const float* bk    = (const float*)d_in[4];
    const float* Wv    = (const float*)d_in[5];
    const float* bv    = (const float*)d_in[6];
    const float* gamma = (const float*)d_in[7];
    float* out = (float*)d_out;

    float* ws = (float*)d_ws;
    size_t off = 0;
    unsigned short* qb = (unsigned short*)(ws + off); off += (size_t)BB * NN * DD / 2 + 64;
    unsigned short* kb = (unsigned short*)(ws + off); off += (size_t)BB * NN * DD / 2 + 64;
    unsigned short* vT = (unsigned short*)(ws + off); off += (size_t)BB * CC * NN / 2 + 64;
    float* obuf = ws + off; off += (size_t)BB * NN * CC;
    float* ssb  = ws + off; off += (size_t)BB * NN;      // contiguous with obuf

    // zero the atomic accumulators (ws is re-poisoned 0xAA before every call)
    hipMemsetAsync(obuf, 0, ((size_t)BB * NN * CC + (size_t)BB * NN) * sizeof(float), stream);

    qkv_kernel<<<BB * 3 * 32, 256, 0, stream>>>(x, Wq, bq, Wk, bk, Wv, bv, qb, kb, vT);
    flash_kernel<<<BB * (NN / 128) * KS, 256, 0, stream>>>(qb, kb, vT, obuf, ssb);
    norm_kernel<<<BB * 128, 256, 0, stream>>>(obuf, ssb, x, gamma, out);
}

// Round 10
// 110.435 us; speedup vs baseline: 1.0399x; 1.0399x over previous
//
#include <hip/hip_runtime.h>
#include <hip/hip_bf16.h>
#include <math.h>

#define BB 4
#define CC 64
#define DD 8
#define NN 4096
#define KS 4
#define KPS (NN / KS)          // 1024 keys per split
#define NT  (KPS / 128)        // 8 tiles per split
#define LOG2E 1.44269504088896340736f

typedef __attribute__((ext_vector_type(4))) short short4v;      // 4 bf16
typedef __attribute__((ext_vector_type(8))) unsigned short ushort8;  // 16B
typedef __attribute__((ext_vector_type(16))) float f32x16;

// Device-pass-only builtins; host pass still semantic-checks __global__ bodies.
#if defined(__HIP_DEVICE_COMPILE__)
  #if __has_builtin(__builtin_amdgcn_mfma_f32_32x32x8bf16_1k)
    #define MFMA32x8(A, B, C) __builtin_amdgcn_mfma_f32_32x32x8bf16_1k(A, B, C, 0, 0, 0)
  #elif __has_builtin(__builtin_amdgcn_mfma_f32_32x32x8_bf16)
    #define MFMA32x8(A, B, C) __builtin_amdgcn_mfma_f32_32x32x8_bf16(A, B, C, 0, 0, 0)
  #else
    #error "no 32x32x8 bf16 MFMA builtin in device pass"
  #endif
  #if __has_builtin(__builtin_amdgcn_exp2f)
    #define EXP2(x) __builtin_amdgcn_exp2f(x)
  #else
    #define EXP2(x) exp2f(x)
  #endif
#else
  static __device__ __host__ inline f32x16 MFMA32x8(short4v, short4v, f32x16 c) { return c; }
  #define EXP2(x) exp2f(x)
#endif

static __device__ inline short4v pack4(float a, float b, float c, float d) {
    union { short4v s; __hip_bfloat162 h[2]; } u;
    u.h[0] = __float22bfloat162_rn(make_float2(a, b));
    u.h[1] = __float22bfloat162_rn(make_float2(c, d));
    return u.s;
}

// ---------------------------------------------------------------------------
// Kernel 1: qkv as MFMA GEMM (unchanged from R8).  Y[96pad,N] = [Wv;Wq;Wk]@x.
// W via float4 vector loads (VGPR A-frags); x streams as B operand.
// rt 0/1 -> vT[B][C][N]; rt 2 -> q/k transposed via LDS to [B][N][8].
// ---------------------------------------------------------------------------
__global__ __launch_bounds__(256) void qkv_kernel(
    const float* __restrict__ x,  const float* __restrict__ Wq, const float* __restrict__ bq,
    const float* __restrict__ Wk, const float* __restrict__ bk,
    const float* __restrict__ Wv, const float* __restrict__ bv,
    unsigned short* __restrict__ qb, unsigned short* __restrict__ kb,
    unsigned short* __restrict__ vT)
{
    __shared__ unsigned short LQ[128 * 8];
    __shared__ unsigned short LK[128 * 8];

    int tid = threadIdx.x;
    int wave = tid >> 6, lane = tid & 63;
    int l32 = lane & 31, h2 = lane >> 5;

    int blk = blockIdx.x;
    int b = blk & (BB - 1);
    int r2 = blk >> 2;
    int rt = r2 % 3;
    int ng = r2 / 3;
    int n0 = ng * 128 + wave * 32;

    short4v af[8];
    #pragma unroll
    for (int s = 0; s < 8; ++s) {
        float4 w4;
        if (rt < 2) {
            w4 = *(const float4*)(Wv + (size_t)(rt * 32 + l32) * CC + s * 8 + 4 * h2);
        } else if (l32 < 8) {
            w4 = *(const float4*)(Wq + (size_t)l32 * CC + s * 8 + 4 * h2);
        } else if (l32 < 16) {
            w4 = *(const float4*)(Wk + (size_t)(l32 - 8) * CC + s * 8 + 4 * h2);
        } else {
            w4 = make_float4(0.f, 0.f, 0.f, 0.f);
        }
        af[s] = pack4(w4.x, w4.y, w4.z, w4.w);
    }

    const float* xb = x + (size_t)b * CC * NN + n0 + l32;
    short4v bf[8];
    #pragma unroll
    for (int s = 0; s < 8; ++s) {
        int c0 = s * 8 + 4 * h2;
        float x0 = xb[(size_t)(c0 + 0) * NN];
        float x1 = xb[(size_t)(c0 + 1) * NN];
        float x2 = xb[(size_t)(c0 + 2) * NN];
        float x3 = xb[(size_t)(c0 + 3) * NN];
        bf[s] = pack4(x0, x1, x2, x3);
    }

    f32x16 acc;
    #pragma unroll
    for (int r = 0; r < 16; ++r) acc[r] = 0.f;
    #pragma unroll
    for (int s = 0; s < 8; ++s)
        acc = MFMA32x8(af[s], bf[s], acc);

    if (rt < 2) {
        #pragma unroll
        for (int r = 0; r < 16; ++r) {
            int row = rt * 32 + (r & 3) + 8 * (r >> 2) + 4 * h2;
            float val = acc[r] + bv[row];
            __hip_bfloat16 hv = __float2bfloat16(val);
            vT[((size_t)b * CC + row) * NN + n0 + l32] = *(unsigned short*)&hv;
        }
    } else {
        short4v qp = pack4((acc[0] + bq[0 + 4 * h2]) * LOG2E,
                           (acc[1] + bq[1 + 4 * h2]) * LOG2E,
                           (acc[2] + bq[2 + 4 * h2]) * LOG2E,
                           (acc[3] + bq[3 + 4 * h2]) * LOG2E);
        short4v kp = pack4(acc[4] + bk[0 + 4 * h2],
                           acc[5] + bk[1 + 4 * h2],
                           acc[6] + bk[2 + 4 * h2],
                           acc[7] + bk[3 + 4 * h2]);
        int nl = wave * 32 + l32;
        *(short4v*)(LQ + (size_t)nl * 8 + 4 * h2) = qp;
        *(short4v*)(LK + (size_t)nl * 8 + 4 * h2) = kp;
        __syncthreads();
        if (tid < 128) {
            ushort8 row = *(const ushort8*)(LQ + (size_t)tid * 8);
            *(ushort8*)(qb + ((size_t)b * NN + ng * 128 + tid) * 8) = row;
        } else {
            int t = tid - 128;
            ushort8 row = *(const ushort8*)(LK + (size_t)t * 8);
            *(ushort8*)(kb + ((size_t)b * NN + ng * 128 + t) * 8) = row;
        }
    }
}

// ---------------------------------------------------------------------------
// Kernel 2: MFMA flash partials, KS=4, LDS DOUBLE-BUFFERED (1 barrier/tile).
// R9 lessons fixed here: (a) no cross-XCD atomics (bf16 accbuf instead);
// (b) kf for tile t+1 is issued BEFORE the V batch, and consumed a full tile
// later, so compute never drains the in-flight prefetch; (c) ds_writes go to
// the spare buffer after compute (vmcnt wait covered by ~600cyc of compute).
// Prefetch beyond the last tile reads adjacent ws allocations (safe garbage).
// Grid: BB * (N/128) * KS = 512 blocks; 2/CU; LDS 33.8KB.
// ---------------------------------------------------------------------------
__global__ __launch_bounds__(256, 4) void flash_kernel(
    const unsigned short* __restrict__ qb, const unsigned short* __restrict__ kb,
    const unsigned short* __restrict__ vT, unsigned short* __restrict__ accb,
    float* __restrict__ sbuf)
{
    __shared__ unsigned short VS[2][64 * 132];
    int tid = threadIdx.x;
    int wave = tid >> 6, lane = tid & 63;
    int l32 = lane & 31, h2 = lane >> 5;

    int blk = blockIdx.x;            // batch in low 2 bits -> XCD locality
    int b = blk & (BB - 1);
    int rest = blk >> 2;
    int split = rest & (KS - 1);
    int qchunk = rest >> 2;
    int n0 = qchunk * 128 + wave * 32;

    short4v qf = *(const short4v*)(qb + ((size_t)b * NN + n0 + l32) * DD + h2 * 4);

    const unsigned short* kbb = kb + (size_t)b * NN * DD;
    const unsigned short* vbb = vT + (size_t)b * CC * NN;
    int m0 = split * KPS;

    int cch = tid >> 4, kg = tid & 15;
    int kgx = (kg ^ (cch & 3)) * 8;

    f32x16 o0, o1, zz;
    #pragma unroll
    for (int r = 0; r < 16; ++r) { o0[r] = 0.f; o1[r] = 0.f; zz[r] = 0.f; }
    float s0 = 0.f, s1 = 0.f, s2 = 0.f, s3 = 0.f;

    // tile 0: k frags first, then V batch
    short4v kf[4];
    #pragma unroll
    for (int s = 0; s < 4; ++s)
        kf[s] = *(const short4v*)(kbb + (size_t)(m0 + s * 32 + l32) * DD + h2 * 4);
    ushort8 w0 = *(const ushort8*)(vbb + (size_t)(cch)      * NN + m0 + kg * 8);
    ushort8 w1 = *(const ushort8*)(vbb + (size_t)(16 + cch) * NN + m0 + kg * 8);
    ushort8 w2 = *(const ushort8*)(vbb + (size_t)(32 + cch) * NN + m0 + kg * 8);
    ushort8 w3 = *(const ushort8*)(vbb + (size_t)(48 + cch) * NN + m0 + kg * 8);
    *(ushort8*)(VS[0] + (size_t)(cch)      * 132 + kgx) = w0;
    *(ushort8*)(VS[0] + (size_t)(16 + cch) * 132 + kgx) = w1;
    *(ushort8*)(VS[0] + (size_t)(32 + cch) * 132 + kgx) = w2;
    *(ushort8*)(VS[0] + (size_t)(48 + cch) * 132 + kgx) = w3;

    int buf = 0;
    for (int tile = 0; tile < NT; ++tile) {
        __syncthreads();                       // VS[buf] ready

        // prefetch tile+1: kf first (consumed next tile), then V batch
        int mn = m0 + (tile + 1) * 128;        // overrun reads are safe garbage
        short4v kn[4];
        #pragma unroll
        for (int s = 0; s < 4; ++s)
            kn[s] = *(const short4v*)(kbb + (size_t)(mn + s * 32 + l32) * DD + h2 * 4);
        w0 = *(const ushort8*)(vbb + (size_t)(cch)      * NN + mn + kg * 8);
        w1 = *(const ushort8*)(vbb + (size_t)(16 + cch) * NN + mn + kg * 8);
        w2 = *(const ushort8*)(vbb + (size_t)(32 + cch) * NN + mn + kg * 8);
        w3 = *(const ushort8*)(vbb + (size_t)(48 + cch) * NN + mn + kg * 8);

        const unsigned short* Vb = VS[buf];
        #pragma unroll
        for (int sub = 0; sub < 4; ++sub) {
            f32x16 st = MFMA32x8(kf[sub], qf, zz);
            float w[16];
            #pragma unroll
            for (int r = 0; r < 16; ++r) w[r] = EXP2(st[r]);
            s0 += (w[0] + w[1]) + (w[2] + w[3]);
            s1 += (w[4] + w[5]) + (w[6] + w[7]);
            s2 += (w[8] + w[9]) + (w[10] + w[11]);
            s3 += (w[12] + w[13]) + (w[14] + w[15]);

            union { short4v s; __hip_bfloat162 h[2]; } u[4];
            #pragma unroll
            for (int g = 0; g < 4; ++g) {
                u[g].h[0] = __float22bfloat162_rn(make_float2(w[4 * g],     w[4 * g + 1]));
                u[g].h[1] = __float22bfloat162_rn(make_float2(w[4 * g + 2], w[4 * g + 3]));
            }
            #pragma unroll
            for (int g = 0; g < 4; ++g) {
                int go = ((sub * 4 + g) ^ (l32 & 3)) * 8 + h2 * 4;
                short4v vf0 = *(const short4v*)(Vb + (size_t)(l32)      * 132 + go);
                short4v vf1 = *(const short4v*)(Vb + (size_t)(32 + l32) * 132 + go);
                o0 = MFMA32x8(u[g].s, vf0, o0);
                o1 = MFMA32x8(u[g].s, vf1, o1);
            }
        }

        if (tile != NT - 1) {
            unsigned short* Vn = VS[buf ^ 1];   // spare: nobody reads it now
            *(ushort8*)(Vn + (size_t)(cch)      * 132 + kgx) = w0;
            *(ushort8*)(Vn + (size_t)(16 + cch) * 132 + kgx) = w1;
            *(ushort8*)(Vn + (size_t)(32 + cch) * 132 + kgx) = w2;
            *(ushort8*)(Vn + (size_t)(48 + cch) * 132 + kgx) = w3;
            #pragma unroll
            for (int s = 0; s < 4; ++s) kf[s] = kn[s];
        }
        buf ^= 1;
    }

    // partials: bf16 accbuf [b][split][n][c] (coalesced, no atomics)
    __hip_bfloat16* ab = (__hip_bfloat16*)accb + (((size_t)(b * KS + split)) * NN + n0) * CC;
    #pragma unroll
    for (int r = 0; r < 16; ++r) {
        int qrow = (r & 3) + 8 * (r >> 2) + 4 * h2;
        ab[(size_t)qrow * CC + l32]      = __float2bfloat16(o0[r]);
        ab[(size_t)qrow * CC + 32 + l32] = __float2bfloat16(o1[r]);
    }
    float ssum = (s0 + s1) + (s2 + s3);
    ssum += __shfl_xor(ssum, 32);
    if (lane < 32)
        sbuf[(size_t)(b * KS + split) * NN + n0 + l32] = ssum;
}

// ---------------------------------------------------------------------------
// Kernel 3: reduce KS=4 splits (ushort8 = 16B/lane coalesced reads),
// normalize, gamma*o + x with LDS transpose.  Grid: B*128 blocks (32 n each).
// ---------------------------------------------------------------------------
__global__ __launch_bounds__(256) void norm_kernel(
    const unsigned short* __restrict__ accb, const float* __restrict__ sbuf,
    const float* __restrict__ x, const float* __restrict__ gamma,
    float* __restrict__ out)
{
    __shared__ float tile[32 * 65];
    __shared__ float stl[32];
    int blk = blockIdx.x;            // B * 128
    int b = blk >> 7;
    int n0 = (blk & 127) * 32;
    int tid = threadIdx.x;

    if (tid < 32) {
        float st = 0.f;
        #pragma unroll
        for (int sp = 0; sp < KS; ++sp)
            st += sbuf[(size_t)(b * KS + sp) * NN + n0 + tid];
        stl[tid] = 1.0f / st;
    }

    int nl = tid >> 3, cg = tid & 7;   // 32 positions x 8 channel-groups
    float a[8];
    #pragma unroll
    for (int e = 0; e < 8; ++e) a[e] = 0.f;
    #pragma unroll
    for (int sp = 0; sp < KS; ++sp) {
        ushort8 v = *(const ushort8*)(accb + (((size_t)(b * KS + sp) * NN) + n0 + nl) * CC + cg * 8);
        #pragma unroll
        for (int e = 0; e < 8; ++e)
            a[e] += __uint_as_float(((unsigned)v[e]) << 16);
    }
    #pragma unroll
    for (int e = 0; e < 8; ++e)
        tile[nl * 65 + cg * 8 + e] = a[e];
    __syncthreads();

    float g = gamma[0];
    #pragma unroll
    for (int p = 0; p < 8; ++p) {
        int idx = p * 256 + tid;
        int c = idx >> 5, n_l = idx & 31;
        size_t xi = ((size_t)b * CC + c) * NN + n0 + n_l;
        out[xi] = g * tile[n_l * 65 + c] * stl[n_l] + x[xi];
    }
}

// ---------------------------------------------------------------------------
extern "C" void kernel_launch(void* const* d_in, const int* in_sizes, int n_in,
                              void* d_out, int out_size, void* d_ws, size_t ws_size,
                              hipStream_t stream)
{
    const float* x     = (const float*)d_in[0];
    const float* Wq    = (const float*)d_in[1];
    const float* bq    = (const float*)d_in[2];
    const float* Wk    = (const float*)d_in[3];
    const float* bk    = (const float*)d_in[4];
    const float* Wv    = (const float*)d_in[5];
    const float* bv    = (const float*)d_in[6];
    const float* gamma = (const float*)d_in[7];
    float* out = (float*)d_out;

    float* ws = (float*)d_ws;
    size_t off = 0;
    unsigned short* qb = (unsigned short*)(ws + off); off += (size_t)BB * NN * DD / 2 + 64;
    unsigned short* kb = (unsigned short*)(ws + off); off += (size_t)BB * NN * DD / 2 + 64;
    unsigned short* vT = (unsigned short*)(ws + off); off += (size_t)BB * CC * NN / 2 + 64;
    unsigned short* accb = (unsigned short*)(ws + off); off += (size_t)BB * KS * NN * CC / 2 + 64;
    float* sbuf = ws + off; off += (size_t)BB * KS * NN;

    qkv_kernel<<<BB * 3 * 32, 256, 0, stream>>>(x, Wq, bq, Wk, bk, Wv, bv, qb, kb, vT);
    flash_kernel<<<BB * (NN / 128) * KS, 256, 0, stream>>>(qb, kb, vT, accb, sbuf);
    norm_kernel<<<BB * 128, 256, 0, stream>>>(accb, sbuf, x, gamma, out);
}